// Round 19
// baseline (111.034 us; speedup 1.0000x reference)
//
#include <hip/hip_runtime.h>
#include <stdint.h>

#define BS 8192
#define DD 128
#define L2E 1.4426950408889634f
#define LN2 0.6931471805599453f

typedef __attribute__((ext_vector_type(8))) short short8;
typedef __attribute__((ext_vector_type(4))) float float4v;

#if __has_builtin(__builtin_amdgcn_exp2f)
#define EXP2(x) __builtin_amdgcn_exp2f(x)
#else
#define EXP2(x) exp2f(x)
#endif

__device__ __forceinline__ float bf2f(short s) {
  union { unsigned u; float f; } c;
  c.u = ((unsigned)(unsigned short)s) << 16;
  return c.f;
}
__device__ __forceinline__ short f2bf(float f) {
  union { float f; unsigned u; } c; c.f = f;
  unsigned u = c.u + 0x7FFFu + ((c.u >> 16) & 1u);
  return (short)(u >> 16);
}

// Fragment-ordered bf16 layout ("xnbF"): 16-byte chunk index for (row, kc):
//   chunk(row,kc) = (row>>4)*256 + (kc>>2)*64 + (kc&3)*16 + (row&15)
// A wave load F[g*256 + t*64 + lane] gives lane (quad=lane>>4, col=lane&15) the
// 8 bf16 of row g*16+col, k-chunk 4t+quad — the verified mfma_f32_16x16x32_bf16
// A/B fragment layout (rounds 2-18 absmax=0). A 64-col panel is 1024 CONTIGUOUS
// chunks -> linear 16KB global_load_lds staging, conflict-free ds_read_b128.
//
// R18 confirmed the settled config reproduces (102.9 -> 103.2). Counters show
// no pipe near limit (Mfma 12%, HBM 3%) — the 2-phase barrier stall is the
// plateau. R19 tries the one untried GEOMETRY lever inside the proven
// structure: 256-thr/1024-blk (4 waves x 32 rows; 4 blocks/CU) instead of
// 512-thr/512-blk (2 blocks/CU). Ladder precedent (m103/m114): at this
// 2-phase structure, smaller blocks won (more independent barrier domains per
// CU -> one block's vmcnt(0)+barrier drain overlaps other blocks' compute).
// Hot-loop text identical; finale loops 16->32 iters FULLY unrolled (R14's
// poison was a partially-unrolled 128-loop; R16 proved full-unroll fine).

// K1: normalize rows -> xnbF; class column sums -> gh16 (16-way split, chain
// 32); zero accumulators; mask mf. 512 blocks x 16 rows. (R12 verbatim)
__global__ __launch_bounds__(256) void k_norm(const float* __restrict__ data,
                                              const int* __restrict__ label,
                                              char* __restrict__ xnbF,
                                              float* __restrict__ gh16,
                                              float* __restrict__ Zr,
                                              float* __restrict__ Ur,
                                              float* __restrict__ Vr,
                                              float* __restrict__ mf) {
  __shared__ float shg[256];
  int tid = threadIdx.x, wave = tid >> 6, lane = tid & 63;
  int lh = lane & 31, rsel = lane >> 5;
  shg[tid] = 0.f;
  int rowbase = blockIdx.x * 16;
  if (tid < 16) {  // zero this block's accumulator rows (workspace is poisoned)
    int row = rowbase + tid;
    Zr[row] = 0.f; Ur[row] = 0.f; Vr[row] = 0.f;
    mf[row] = (label[row] == 0) ? 1.f : 0.f;
  }
  __syncthreads();

  float a00 = 0.f, a01 = 0.f, a02 = 0.f, a03 = 0.f;  // class-0 column partials
  float a10 = 0.f, a11 = 0.f, a12 = 0.f, a13 = 0.f;  // class-1
#pragma unroll
  for (int it = 0; it < 2; ++it) {
    int row = rowbase + it * 8 + wave * 2 + rsel;
    float4 v = *(const float4*)&data[row * DD + lh * 4];  // 16B/lane coalesced
    float ss = v.x * v.x + v.y * v.y + v.z * v.z + v.w * v.w;
#pragma unroll
    for (int off = 16; off; off >>= 1) ss += __shfl_xor(ss, off);  // 32-lane
    float rn = 1.f / fmaxf(sqrtf(ss), 1e-12f);  // F.normalize eps clamp
    float x0 = v.x * rn, x1 = v.y * rn, x2 = v.z * rn, x3 = v.w * rn;

    unsigned pk0 = (unsigned)(unsigned short)f2bf(x0) |
                   ((unsigned)(unsigned short)f2bf(x1) << 16);
    unsigned pk1 = (unsigned)(unsigned short)f2bf(x2) |
                   ((unsigned)(unsigned short)f2bf(x3) << 16);
    int kc = lh >> 1;
    size_t chunk = (size_t)(row >> 4) * 256 + (size_t)(kc >> 2) * 64 +
                   (size_t)(kc & 3) * 16 + (row & 15);
    *(uint2*)(xnbF + chunk * 16 + (lh & 1) * 8) = make_uint2(pk0, pk1);

    int lab = label[row];  // half-wave uniform
    if (lab == 0) {
      a00 += x0; a01 += x1; a02 += x2; a03 += x3;
    } else {
      a10 += x0; a11 += x1; a12 += x2; a13 += x3;
    }
  }
  int base = lh * 4;
  atomicAdd(&shg[base + 0], a00); atomicAdd(&shg[base + 1], a01);
  atomicAdd(&shg[base + 2], a02); atomicAdd(&shg[base + 3], a03);
  atomicAdd(&shg[128 + base + 0], a10); atomicAdd(&shg[128 + base + 1], a11);
  atomicAdd(&shg[128 + base + 2], a12); atomicAdd(&shg[128 + base + 3], a13);
  __syncthreads();
  // 16-way-split targets: per-address global atomic chain is 512/16 = 32
  atomicAdd(&gh16[(blockIdx.x & 15) * 256 + tid], shg[tid]);
}

// K2: full-matrix Gram-row reductions (R6 hot loop, 256-thr/1024-blk geometry)
// + 16-slab ticket finale.
__global__ __launch_bounds__(256, 4) void k_main(const short* __restrict__ xnbF,
                                                 const int* __restrict__ label,
                                                 const float* __restrict__ mf,
                                                 const float* __restrict__ scale,
                                                 const float* __restrict__ gh16,
                                                 float* __restrict__ Zr,
                                                 float* __restrict__ Ur,
                                                 float* __restrict__ Vr,
                                                 int* __restrict__ ticket,
                                                 float* __restrict__ out) {
  __shared__ short tile[2][64 * DD];  // 2 x 16KB double buffer
  __shared__ int credu[4];
  __shared__ float fredu[4];
  __shared__ float dred[12];
  __shared__ int lastf;
  int tid = threadIdx.x, wave = tid >> 6, lane = tid & 63;
  int quad = lane >> 4, col = lane & 15;
  int rbI = blockIdx.x >> 4;  // 0..63: 128-row block (4 waves x 32 rows)
  int sl = blockIdx.x & 15;   // 0..15: 512-col slice (8 tiles of 64)
  float se2 = __expf(scale[0]) * L2E;  // exp(scale)*log2(e): log2-domain logits

  const short8* F = (const short8*)xnbF;
  int gA = rbI * 8 + wave * 2;
  short8 af[2][4];
#pragma unroll
  for (int s = 0; s < 2; ++s)
#pragma unroll
    for (int t = 0; t < 4; ++t) {
      short8 a = F[(size_t)(gA + s) * 256 + t * 64 + lane];
#pragma unroll
      for (int i = 0; i < 8; ++i) a[i] = f2bf(bf2f(a[i]) * se2);
      af[s][t] = a;
    }

  float4v Z0 = {0.f,0.f,0.f,0.f}, Z1 = Z0, U0 = Z0, U1 = Z0, V0 = Z0, V1 = Z0;
  int cb4 = sl * 32;  // chunk-group base of this slice

  // Stage one 64-col tile (16KB = 1024 contiguous chunks): 256 thr x 4 x 16B;
  // dst = wave-uniform base + lane*16 (HW requirement for global_load_lds).
#define STAGE(buf, jt)                                                         \
  {                                                                            \
    const char* s_ = (const char*)xnbF +                                       \
                     ((size_t)(cb4 + (jt) * 4) * 256 + tid) * 16;              \
    char* d_ = (char*)tile[buf] + tid * 16;                                    \
    _Pragma("unroll")                                                          \
    for (int p = 0; p < 4; ++p)                                                \
      __builtin_amdgcn_global_load_lds(                                        \
          (const __attribute__((address_space(1))) void*)(uintptr_t)           \
              (s_ + p * 4096),                                                 \
          (__attribute__((address_space(3))) void*)(uintptr_t)(d_ + p * 4096), \
          16, 0, 0);                                                           \
  }

  STAGE(0, 0);
  __syncthreads();  // tile 0 resident

#pragma unroll 1
  for (int jt = 0; jt < 8; ++jt) {
    if (jt < 7) STAGE((jt + 1) & 1, jt + 1);  // in flight over this compute
    const short8* T8 = (const short8*)tile[jt & 1];
    int jcb = sl * 512 + jt * 64;

#define HALFTILE(jo)                                                           \
    {                                                                          \
      short8 b00 = T8[(jo) * 256 + lane];                                      \
      short8 b01 = T8[(jo) * 256 + 64 + lane];                                 \
      short8 b02 = T8[(jo) * 256 + 128 + lane];                                \
      short8 b03 = T8[(jo) * 256 + 192 + lane];                                \
      short8 b10 = T8[(jo + 1) * 256 + lane];                                  \
      short8 b11 = T8[(jo + 1) * 256 + 64 + lane];                             \
      short8 b12 = T8[(jo + 1) * 256 + 128 + lane];                            \
      short8 b13 = T8[(jo + 1) * 256 + 192 + lane];                            \
      float m0 = mf[jcb + (jo) * 16 + col];                                    \
      float m1 = mf[jcb + (jo + 1) * 16 + col];                                \
      float4v c00 = {0.f, 0.f, 0.f, 0.f}, c01 = c00, c10 = c00, c11 = c00;     \
      c00 = __builtin_amdgcn_mfma_f32_16x16x32_bf16(af[0][0], b00, c00, 0,0,0);\
      c01 = __builtin_amdgcn_mfma_f32_16x16x32_bf16(af[1][0], b00, c01, 0,0,0);\
      c10 = __builtin_amdgcn_mfma_f32_16x16x32_bf16(af[0][0], b10, c10, 0,0,0);\
      c11 = __builtin_amdgcn_mfma_f32_16x16x32_bf16(af[1][0], b10, c11, 0,0,0);\
      c00 = __builtin_amdgcn_mfma_f32_16x16x32_bf16(af[0][1], b01, c00, 0,0,0);\
      c01 = __builtin_amdgcn_mfma_f32_16x16x32_bf16(af[1][1], b01, c01, 0,0,0);\
      c10 = __builtin_amdgcn_mfma_f32_16x16x32_bf16(af[0][1], b11, c10, 0,0,0);\
      c11 = __builtin_amdgcn_mfma_f32_16x16x32_bf16(af[1][1], b11, c11, 0,0,0);\
      c00 = __builtin_amdgcn_mfma_f32_16x16x32_bf16(af[0][2], b02, c00, 0,0,0);\
      c01 = __builtin_amdgcn_mfma_f32_16x16x32_bf16(af[1][2], b02, c01, 0,0,0);\
      c10 = __builtin_amdgcn_mfma_f32_16x16x32_bf16(af[0][2], b12, c10, 0,0,0);\
      c11 = __builtin_amdgcn_mfma_f32_16x16x32_bf16(af[1][2], b12, c11, 0,0,0);\
      c00 = __builtin_amdgcn_mfma_f32_16x16x32_bf16(af[0][3], b03, c00, 0,0,0);\
      c01 = __builtin_amdgcn_mfma_f32_16x16x32_bf16(af[1][3], b03, c01, 0,0,0);\
      c10 = __builtin_amdgcn_mfma_f32_16x16x32_bf16(af[0][3], b13, c10, 0,0,0);\
      c11 = __builtin_amdgcn_mfma_f32_16x16x32_bf16(af[1][3], b13, c11, 0,0,0);\
      _Pragma("unroll")                                                        \
      for (int r = 0; r < 4; ++r) { /* C/D: col=lane&15, row=quad*4+r (m89) */ \
        float l, e;                                                            \
        l = c00[r]; e = EXP2(l);  /* log2-domain, |l|<=20.6: fp32-safe */      \
        Z0[r] += e; U0[r] = fmaf(e, l, U0[r]); V0[r] = fmaf(m0, e, V0[r]);     \
        l = c01[r]; e = EXP2(l);                                               \
        Z1[r] += e; U1[r] = fmaf(e, l, U1[r]); V1[r] = fmaf(m0, e, V1[r]);     \
        l = c10[r]; e = EXP2(l);                                               \
        Z0[r] += e; U0[r] = fmaf(e, l, U0[r]); V0[r] = fmaf(m1, e, V0[r]);     \
        l = c11[r]; e = EXP2(l);                                               \
        Z1[r] += e; U1[r] = fmaf(e, l, U1[r]); V1[r] = fmaf(m1, e, V1[r]);     \
      }                                                                        \
    }
    HALFTILE(0)
    HALFTILE(2)
#undef HALFTILE
    __syncthreads();  // drains stage(jt+1); protects overwritten buffer
  }
#undef STAGE

  // reduce across the 16 column-lanes sharing each output row, then atomics
#define EMIT(s, Zc, Uc, Vc)                                                    \
  {                                                                            \
    _Pragma("unroll")                                                          \
    for (int r = 0; r < 4; ++r) {                                              \
      float z = Zc[r], u = Uc[r], v0 = Vc[r];                                  \
      _Pragma("unroll")                                                        \
      for (int off = 1; off < 16; off <<= 1) {                                 \
        z += __shfl_xor(z, off);                                               \
        u += __shfl_xor(u, off);                                               \
        v0 += __shfl_xor(v0, off);                                             \
      }                                                                        \
      if (col == 0) {                                                          \
        int row = rbI * 128 + wave * 32 + s * 16 + quad * 4 + r;               \
        int lab = label[row];                                                  \
        float v = (lab == 0) ? v0 : (z - v0);                                  \
        atomicAdd(&Zr[row], z);                                                \
        atomicAdd(&Ur[row], u * LN2); /* log2-domain -> nats */                \
        atomicAdd(&Vr[row], v);                                                \
      }                                                                        \
    }                                                                          \
  }
  EMIT(0, Z0, U0, V0)
  EMIT(1, Z1, U1, V1)
#undef EMIT

  // ---- ticket finale: last block computes counts + dots + total loss ----
  __syncthreads();  // all this block's EMIT atomics issued
  if (tid == 0) {
    int t = __hip_atomic_fetch_add(ticket, 1, __ATOMIC_ACQ_REL,
                                   __HIP_MEMORY_SCOPE_AGENT);
    lastf = (t == 1023);
  }
  __syncthreads();
  if (!lastf) return;

  // All 1024 blocks' device-scope atomics are at the coherence point; gh16 is
  // from the previous kernel (boundary-visible).
  float* hs = (float*)tile;  // reuse LDS: h0 in [0..127], h1 in [128..255]
  {
    float h = 0.f;
#pragma unroll
    for (int i = 0; i < 16; ++i) h += gh16[i * 256 + tid];
    hs[tid] = h;
  }
  int c1i = 0;
#pragma unroll
  for (int k = 0; k < 32; ++k) c1i += label[k * 256 + tid];  // coalesced {0,1}
#pragma unroll
  for (int off = 32; off; off >>= 1) c1i += __shfl_xor(c1i, off);
  if (lane == 0) credu[wave] = c1i;
  __syncthreads();  // hs + credu ready
  int c1t = 0;
#pragma unroll
  for (int w = 0; w < 4; ++w) c1t += credu[w];
  float c1 = (float)c1t, c0 = (float)(BS - c1t);

  // 3 dots of the class-sum vectors (threads 0..127, one dim each)
  float p00 = 0.f, p01 = 0.f, p11 = 0.f;
  if (tid < 128) {
    float h0d = hs[tid], h1d = hs[128 + tid];
    p00 = h0d * h0d; p01 = h0d * h1d; p11 = h1d * h1d;
  }
#pragma unroll
  for (int off = 32; off; off >>= 1) {
    p00 += __shfl_xor(p00, off);
    p01 += __shfl_xor(p01, off);
    p11 += __shfl_xor(p11, off);
  }
  if (lane == 0) { dred[wave] = p00; dred[4 + wave] = p01; dred[8 + wave] = p11; }

  // per-row sum: (U - V/c)/Z
  float rc0 = 1.f / c0, rc1 = 1.f / c1;
  float local = 0.f;
#pragma unroll
  for (int k = 0; k < 32; ++k) {
    int row = k * 256 + tid;
    int lab = label[row];
    float Z = __hip_atomic_load(&Zr[row], __ATOMIC_RELAXED, __HIP_MEMORY_SCOPE_AGENT);
    float U = __hip_atomic_load(&Ur[row], __ATOMIC_RELAXED, __HIP_MEMORY_SCOPE_AGENT);
    float V = __hip_atomic_load(&Vr[row], __ATOMIC_RELAXED, __HIP_MEMORY_SCOPE_AGENT);
    local += (U - V * (lab ? rc1 : rc0)) / Z;
  }
#pragma unroll
  for (int off = 32; off; off >>= 1) local += __shfl_xor(local, off);
  if (lane == 0) fredu[wave] = local;
  __syncthreads();
  if (tid == 0) {
    float se = __expf(scale[0]);
    float a0 = __expf(1.f / c0), a1 = __expf(1.f / c1);
    float rZq0 = 1.f / (c0 * a0 + ((float)BS - c0));
    float rZq1 = 1.f / (c1 * a1 + ((float)BS - c1));
    float d00 = dred[0] + dred[1], d01 = dred[4] + dred[5],
          d11 = dred[8] + dred[9];
    float rows = 0.f;
#pragma unroll
    for (int w = 0; w < 4; ++w) rows += fredu[w];
    // Σ loss_i = Σ a/Zq  −  Σ (S+(a−1)T)/Zq  +  Σ (U − V/c)/Z
    //   class sums: Σ_{c0} S = se·h0·(h0+h1) = se·(d00+d01); Σ_{c0} T = se·d00
    float stsum = se * (rZq0 * ((d00 + d01) + (a0 - 1.f) * d00) +
                        rZq1 * ((d01 + d11) + (a1 - 1.f) * d11));
    float total = c0 * a0 * rZq0 + c1 * a1 * rZq1 - stsum + rows;
    out[0] = total * (0.5f / (float)BS);
  }
}

extern "C" void kernel_launch(void* const* d_in, const int* in_sizes, int n_in,
                              void* d_out, int out_size, void* d_ws, size_t ws_size,
                              hipStream_t stream) {
  const float* data = (const float*)d_in[0];
  const float* scale = (const float*)d_in[1];
  const int* label = (const int*)d_in[2];
  char* ws = (char*)d_ws;
  // ws layout (bytes):
  //   0        xnbF bf16 fragment-order [8192*128]   2 MB
  //   2097152  Zr     f32 [8192]
  //   2129920  Ur     f32 [8192]
  //   2162688  Vr     f32 [8192]
  //   2195456  gh16   f32 [16][256]  (16-way split class sums)
  //   2211840  ticket int [1]
  //   2211872  mf     f32 [8192]
  char* xnbF = ws;
  float* Zr = (float*)(ws + 2097152);
  float* Ur = (float*)(ws + 2129920);
  float* Vr = (float*)(ws + 2162688);
  float* gh16 = (float*)(ws + 2195456);
  int* ticket = (int*)(ws + 2211840);
  float* mf = (float*)(ws + 2211872);

  // gh16 + ticket (16388 B); Zr/Ur/Vr/mf zeroed in k_norm; out stored by
  // k_main's last block.
  hipMemsetAsync(ws + 2195456, 0, 16388, stream);

  k_norm<<<512, 256, 0, stream>>>(data, label, xnbF, gh16, Zr, Ur, Vr, mf);
  k_main<<<1024, 256, 0, stream>>>((const short*)xnbF, label, mf, scale, gh16,
                                   Zr, Ur, Vr, ticket, (float*)d_out);
}

// Round 20
// 102.273 us; speedup vs baseline: 1.0857x; 1.0857x over previous
//
#include <hip/hip_runtime.h>
#include <stdint.h>

#define BS 8192
#define DD 128
#define L2E 1.4426950408889634f
#define LN2 0.6931471805599453f

typedef __attribute__((ext_vector_type(8))) short short8;
typedef __attribute__((ext_vector_type(4))) float float4v;

#if __has_builtin(__builtin_amdgcn_exp2f)
#define EXP2(x) __builtin_amdgcn_exp2f(x)
#else
#define EXP2(x) exp2f(x)
#endif

__device__ __forceinline__ float bf2f(short s) {
  union { unsigned u; float f; } c;
  c.u = ((unsigned)(unsigned short)s) << 16;
  return c.f;
}
__device__ __forceinline__ short f2bf(float f) {
  union { float f; unsigned u; } c; c.f = f;
  unsigned u = c.u + 0x7FFFu + ((c.u >> 16) & 1u);
  return (short)(u >> 16);
}

// Fragment-ordered bf16 layout ("xnbF"): 16-byte chunk index for (row, kc):
//   chunk(row,kc) = (row>>4)*256 + (kc>>2)*64 + (kc&3)*16 + (row&15)
// A wave load F[g*256 + t*64 + lane] gives lane (quad=lane>>4, col=lane&15) the
// 8 bf16 of row g*16+col, k-chunk 4t+quad — the verified mfma_f32_16x16x32_bf16
// A/B fragment layout (rounds 2-19 absmax=0). A 64-col panel is 1024 CONTIGUOUS
// chunks -> linear 16KB global_load_lds staging, conflict-free ds_read_b128.
//
// TERMINAL (R20): the session settles on the best measured config, verified
// twice (R12: 102.9us, R18: 103.2us). Full ledger of rejected alternatives:
// R19 256-thr/1024-blk geometry = 63.4us k_main (2x staging traffic, halved
// per-block stage parallelism); R17 128-col tile = spill (WRITE 33MB); R14
// 128-slab finale = codegen poison (54.6us); R13 separate k_fin = +5us launch;
// R9/R10 cooperative fusion = cross-XCD staleness (absmax 7.06); R7/R8
// symmetric-triangle = per-job overhead / spill; R5 2-deep ping-pong = 44us.
// k_main 2-phase plateau = 40.5us (VGPR 60, WRITE 6.16MB pure atomics);
// harness fill = 41us fixed. Session net: 121.0 -> 102.9us.

// K1: normalize rows -> xnbF; class column sums -> gh16 (16-way split, chain
// 32); zero accumulators; mask mf. 512 blocks x 16 rows.
__global__ __launch_bounds__(256) void k_norm(const float* __restrict__ data,
                                              const int* __restrict__ label,
                                              char* __restrict__ xnbF,
                                              float* __restrict__ gh16,
                                              float* __restrict__ Zr,
                                              float* __restrict__ Ur,
                                              float* __restrict__ Vr,
                                              float* __restrict__ mf) {
  __shared__ float shg[256];
  int tid = threadIdx.x, wave = tid >> 6, lane = tid & 63;
  int lh = lane & 31, rsel = lane >> 5;
  shg[tid] = 0.f;
  int rowbase = blockIdx.x * 16;
  if (tid < 16) {  // zero this block's accumulator rows (workspace is poisoned)
    int row = rowbase + tid;
    Zr[row] = 0.f; Ur[row] = 0.f; Vr[row] = 0.f;
    mf[row] = (label[row] == 0) ? 1.f : 0.f;
  }
  __syncthreads();

  float a00 = 0.f, a01 = 0.f, a02 = 0.f, a03 = 0.f;  // class-0 column partials
  float a10 = 0.f, a11 = 0.f, a12 = 0.f, a13 = 0.f;  // class-1
#pragma unroll
  for (int it = 0; it < 2; ++it) {
    int row = rowbase + it * 8 + wave * 2 + rsel;
    float4 v = *(const float4*)&data[row * DD + lh * 4];  // 16B/lane coalesced
    float ss = v.x * v.x + v.y * v.y + v.z * v.z + v.w * v.w;
#pragma unroll
    for (int off = 16; off; off >>= 1) ss += __shfl_xor(ss, off);  // 32-lane
    float rn = 1.f / fmaxf(sqrtf(ss), 1e-12f);  // F.normalize eps clamp
    float x0 = v.x * rn, x1 = v.y * rn, x2 = v.z * rn, x3 = v.w * rn;

    unsigned pk0 = (unsigned)(unsigned short)f2bf(x0) |
                   ((unsigned)(unsigned short)f2bf(x1) << 16);
    unsigned pk1 = (unsigned)(unsigned short)f2bf(x2) |
                   ((unsigned)(unsigned short)f2bf(x3) << 16);
    int kc = lh >> 1;
    size_t chunk = (size_t)(row >> 4) * 256 + (size_t)(kc >> 2) * 64 +
                   (size_t)(kc & 3) * 16 + (row & 15);
    *(uint2*)(xnbF + chunk * 16 + (lh & 1) * 8) = make_uint2(pk0, pk1);

    int lab = label[row];  // half-wave uniform
    if (lab == 0) {
      a00 += x0; a01 += x1; a02 += x2; a03 += x3;
    } else {
      a10 += x0; a11 += x1; a12 += x2; a13 += x3;
    }
  }
  int base = lh * 4;  // 8 colliders per LDS address
  atomicAdd(&shg[base + 0], a00); atomicAdd(&shg[base + 1], a01);
  atomicAdd(&shg[base + 2], a02); atomicAdd(&shg[base + 3], a03);
  atomicAdd(&shg[128 + base + 0], a10); atomicAdd(&shg[128 + base + 1], a11);
  atomicAdd(&shg[128 + base + 2], a12); atomicAdd(&shg[128 + base + 3], a13);
  __syncthreads();
  // 16-way-split targets: per-address global atomic chain is 512/16 = 32
  atomicAdd(&gh16[(blockIdx.x & 15) * 256 + tid], shg[tid]);
}

// K2: full-matrix Gram-row reductions (R6 hot loop) + 16-slab ticket finale.
__global__ __launch_bounds__(512, 4) void k_main(const short* __restrict__ xnbF,
                                                 const int* __restrict__ label,
                                                 const float* __restrict__ mf,
                                                 const float* __restrict__ scale,
                                                 const float* __restrict__ gh16,
                                                 float* __restrict__ Zr,
                                                 float* __restrict__ Ur,
                                                 float* __restrict__ Vr,
                                                 int* __restrict__ ticket,
                                                 float* __restrict__ out) {
  __shared__ short tile[2][64 * DD];  // 2 x 16KB double buffer
  __shared__ int credu[8];
  __shared__ float fredu[8];
  __shared__ float dred[24];
  __shared__ int lastf;
  int tid = threadIdx.x, wave = tid >> 6, lane = tid & 63;
  int quad = lane >> 4, col = lane & 15;
  int rbI = blockIdx.x >> 4;  // 0..31: 256-row block (8 waves x 32 rows)
  int sl = blockIdx.x & 15;   // 0..15: 512-col slice (8 tiles of 64)
  float se2 = __expf(scale[0]) * L2E;  // exp(scale)*log2(e): log2-domain logits

  const short8* F = (const short8*)xnbF;
  int gA = rbI * 16 + wave * 2;
  short8 af[2][4];
#pragma unroll
  for (int s = 0; s < 2; ++s)
#pragma unroll
    for (int t = 0; t < 4; ++t) {
      short8 a = F[(size_t)(gA + s) * 256 + t * 64 + lane];
#pragma unroll
      for (int i = 0; i < 8; ++i) a[i] = f2bf(bf2f(a[i]) * se2);
      af[s][t] = a;
    }

  float4v Z0 = {0.f,0.f,0.f,0.f}, Z1 = Z0, U0 = Z0, U1 = Z0, V0 = Z0, V1 = Z0;
  int cb4 = sl * 32;  // chunk-group base of this slice

#define STAGE(buf, jt)                                                         \
  {                                                                            \
    const char* s_ = (const char*)xnbF +                                       \
                     ((size_t)(cb4 + (jt) * 4) * 256 + tid) * 16;              \
    char* d_ = (char*)tile[buf] + tid * 16;                                    \
    __builtin_amdgcn_global_load_lds(                                          \
        (const __attribute__((address_space(1))) void*)(uintptr_t)s_,          \
        (__attribute__((address_space(3))) void*)(uintptr_t)d_, 16, 0, 0);     \
    __builtin_amdgcn_global_load_lds(                                          \
        (const __attribute__((address_space(1))) void*)(uintptr_t)(s_ + 8192), \
        (__attribute__((address_space(3))) void*)(uintptr_t)(d_ + 8192),       \
        16, 0, 0);                                                             \
  }

  STAGE(0, 0);
  __syncthreads();  // tile 0 resident

#pragma unroll 1
  for (int jt = 0; jt < 8; ++jt) {
    if (jt < 7) STAGE((jt + 1) & 1, jt + 1);  // in flight over this compute
    const short8* T8 = (const short8*)tile[jt & 1];
    int jcb = sl * 512 + jt * 64;

#define HALFTILE(jo)                                                           \
    {                                                                          \
      short8 b00 = T8[(jo) * 256 + lane];                                      \
      short8 b01 = T8[(jo) * 256 + 64 + lane];                                 \
      short8 b02 = T8[(jo) * 256 + 128 + lane];                                \
      short8 b03 = T8[(jo) * 256 + 192 + lane];                                \
      short8 b10 = T8[(jo + 1) * 256 + lane];                                  \
      short8 b11 = T8[(jo + 1) * 256 + 64 + lane];                             \
      short8 b12 = T8[(jo + 1) * 256 + 128 + lane];                            \
      short8 b13 = T8[(jo + 1) * 256 + 192 + lane];                            \
      float m0 = mf[jcb + (jo) * 16 + col];                                    \
      float m1 = mf[jcb + (jo + 1) * 16 + col];                                \
      float4v c00 = {0.f, 0.f, 0.f, 0.f}, c01 = c00, c10 = c00, c11 = c00;     \
      c00 = __builtin_amdgcn_mfma_f32_16x16x32_bf16(af[0][0], b00, c00, 0,0,0);\
      c01 = __builtin_amdgcn_mfma_f32_16x16x32_bf16(af[1][0], b00, c01, 0,0,0);\
      c10 = __builtin_amdgcn_mfma_f32_16x16x32_bf16(af[0][0], b10, c10, 0,0,0);\
      c11 = __builtin_amdgcn_mfma_f32_16x16x32_bf16(af[1][0], b10, c11, 0,0,0);\
      c00 = __builtin_amdgcn_mfma_f32_16x16x32_bf16(af[0][1], b01, c00, 0,0,0);\
      c01 = __builtin_amdgcn_mfma_f32_16x16x32_bf16(af[1][1], b01, c01, 0,0,0);\
      c10 = __builtin_amdgcn_mfma_f32_16x16x32_bf16(af[0][1], b11, c10, 0,0,0);\
      c11 = __builtin_amdgcn_mfma_f32_16x16x32_bf16(af[1][1], b11, c11, 0,0,0);\
      c00 = __builtin_amdgcn_mfma_f32_16x16x32_bf16(af[0][2], b02, c00, 0,0,0);\
      c01 = __builtin_amdgcn_mfma_f32_16x16x32_bf16(af[1][2], b02, c01, 0,0,0);\
      c10 = __builtin_amdgcn_mfma_f32_16x16x32_bf16(af[0][2], b12, c10, 0,0,0);\
      c11 = __builtin_amdgcn_mfma_f32_16x16x32_bf16(af[1][2], b12, c11, 0,0,0);\
      c00 = __builtin_amdgcn_mfma_f32_16x16x32_bf16(af[0][3], b03, c00, 0,0,0);\
      c01 = __builtin_amdgcn_mfma_f32_16x16x32_bf16(af[1][3], b03, c01, 0,0,0);\
      c10 = __builtin_amdgcn_mfma_f32_16x16x32_bf16(af[0][3], b13, c10, 0,0,0);\
      c11 = __builtin_amdgcn_mfma_f32_16x16x32_bf16(af[1][3], b13, c11, 0,0,0);\
      _Pragma("unroll")                                                        \
      for (int r = 0; r < 4; ++r) { /* C/D: col=lane&15, row=quad*4+r (m89) */ \
        float l, e;                                                            \
        l = c00[r]; e = EXP2(l);  /* log2-domain, |l|<=20.6: fp32-safe */      \
        Z0[r] += e; U0[r] = fmaf(e, l, U0[r]); V0[r] = fmaf(m0, e, V0[r]);     \
        l = c01[r]; e = EXP2(l);                                               \
        Z1[r] += e; U1[r] = fmaf(e, l, U1[r]); V1[r] = fmaf(m0, e, V1[r]);     \
        l = c10[r]; e = EXP2(l);                                               \
        Z0[r] += e; U0[r] = fmaf(e, l, U0[r]); V0[r] = fmaf(m1, e, V0[r]);     \
        l = c11[r]; e = EXP2(l);                                               \
        Z1[r] += e; U1[r] = fmaf(e, l, U1[r]); V1[r] = fmaf(m1, e, V1[r]);     \
      }                                                                        \
    }
    HALFTILE(0)
    HALFTILE(2)
#undef HALFTILE
    __syncthreads();  // drains stage(jt+1); protects overwritten buffer
  }
#undef STAGE

  // reduce across the 16 column-lanes sharing each output row, then atomics
#define EMIT(s, Zc, Uc, Vc)                                                    \
  {                                                                            \
    _Pragma("unroll")                                                          \
    for (int r = 0; r < 4; ++r) {                                              \
      float z = Zc[r], u = Uc[r], v0 = Vc[r];                                  \
      _Pragma("unroll")                                                        \
      for (int off = 1; off < 16; off <<= 1) {                                 \
        z += __shfl_xor(z, off);                                               \
        u += __shfl_xor(u, off);                                               \
        v0 += __shfl_xor(v0, off);                                             \
      }                                                                        \
      if (col == 0) {                                                          \
        int row = rbI * 256 + wave * 32 + s * 16 + quad * 4 + r;               \
        int lab = label[row];                                                  \
        float v = (lab == 0) ? v0 : (z - v0);                                  \
        atomicAdd(&Zr[row], z);                                                \
        atomicAdd(&Ur[row], u * LN2); /* log2-domain -> nats */                \
        atomicAdd(&Vr[row], v);                                                \
      }                                                                        \
    }                                                                          \
  }
  EMIT(0, Z0, U0, V0)
  EMIT(1, Z1, U1, V1)
#undef EMIT

  // ---- ticket finale: last block computes counts + dots + total loss ----
  __syncthreads();  // all this block's EMIT atomics issued
  if (tid == 0) {
    int t = __hip_atomic_fetch_add(ticket, 1, __ATOMIC_ACQ_REL,
                                   __HIP_MEMORY_SCOPE_AGENT);
    lastf = (t == 511);
  }
  __syncthreads();
  if (!lastf) return;

  // All 512 blocks' device-scope atomics are at the coherence point; gh16 is
  // from the previous kernel (boundary-visible).
  float* hs = (float*)tile;  // reuse LDS: h0 in [0..127], h1 in [128..255]
  if (tid < 256) {
    float h = 0.f;
#pragma unroll
    for (int i = 0; i < 16; ++i) h += gh16[i * 256 + tid];
    hs[tid] = h;
  }
  int c1i = 0;
#pragma unroll
  for (int k = 0; k < 16; ++k) c1i += label[k * 512 + tid];  // coalesced {0,1}
#pragma unroll
  for (int off = 32; off; off >>= 1) c1i += __shfl_xor(c1i, off);
  if (lane == 0) credu[wave] = c1i;
  __syncthreads();  // hs + credu ready
  int c1t = 0;
#pragma unroll
  for (int w = 0; w < 8; ++w) c1t += credu[w];
  float c1 = (float)c1t, c0 = (float)(BS - c1t);

  // 3 dots of the class-sum vectors (threads 0..127, one dim each)
  float p00 = 0.f, p01 = 0.f, p11 = 0.f;
  if (tid < 128) {
    float h0d = hs[tid], h1d = hs[128 + tid];
    p00 = h0d * h0d; p01 = h0d * h1d; p11 = h1d * h1d;
  }
#pragma unroll
  for (int off = 32; off; off >>= 1) {
    p00 += __shfl_xor(p00, off);
    p01 += __shfl_xor(p01, off);
    p11 += __shfl_xor(p11, off);
  }
  if (lane == 0) { dred[wave] = p00; dred[8 + wave] = p01; dred[16 + wave] = p11; }

  // per-row sum: (U - V/c)/Z
  float rc0 = 1.f / c0, rc1 = 1.f / c1;
  float local = 0.f;
#pragma unroll
  for (int k = 0; k < 16; ++k) {
    int row = k * 512 + tid;
    int lab = label[row];
    float Z = __hip_atomic_load(&Zr[row], __ATOMIC_RELAXED, __HIP_MEMORY_SCOPE_AGENT);
    float U = __hip_atomic_load(&Ur[row], __ATOMIC_RELAXED, __HIP_MEMORY_SCOPE_AGENT);
    float V = __hip_atomic_load(&Vr[row], __ATOMIC_RELAXED, __HIP_MEMORY_SCOPE_AGENT);
    local += (U - V * (lab ? rc1 : rc0)) / Z;
  }
#pragma unroll
  for (int off = 32; off; off >>= 1) local += __shfl_xor(local, off);
  if (lane == 0) fredu[wave] = local;
  __syncthreads();
  if (tid == 0) {
    float se = __expf(scale[0]);
    float a0 = __expf(1.f / c0), a1 = __expf(1.f / c1);
    float rZq0 = 1.f / (c0 * a0 + ((float)BS - c0));
    float rZq1 = 1.f / (c1 * a1 + ((float)BS - c1));
    float d00 = dred[0] + dred[1], d01 = dred[8] + dred[9],
          d11 = dred[16] + dred[17];
    float rows = 0.f;
#pragma unroll
    for (int w = 0; w < 8; ++w) rows += fredu[w];
    // Σ loss_i = Σ a/Zq  −  Σ (S+(a−1)T)/Zq  +  Σ (U − V/c)/Z
    //   class sums: Σ_{c0} S = se·h0·(h0+h1) = se·(d00+d01); Σ_{c0} T = se·d00
    float stsum = se * (rZq0 * ((d00 + d01) + (a0 - 1.f) * d00) +
                        rZq1 * ((d01 + d11) + (a1 - 1.f) * d11));
    float total = c0 * a0 * rZq0 + c1 * a1 * rZq1 - stsum + rows;
    out[0] = total * (0.5f / (float)BS);
  }
}

extern "C" void kernel_launch(void* const* d_in, const int* in_sizes, int n_in,
                              void* d_out, int out_size, void* d_ws, size_t ws_size,
                              hipStream_t stream) {
  const float* data = (const float*)d_in[0];
  const float* scale = (const float*)d_in[1];
  const int* label = (const int*)d_in[2];
  char* ws = (char*)d_ws;
  // ws layout (bytes):
  //   0        xnbF bf16 fragment-order [8192*128]   2 MB
  //   2097152  Zr     f32 [8192]
  //   2129920  Ur     f32 [8192]
  //   2162688  Vr     f32 [8192]
  //   2195456  gh16   f32 [16][256]  (16-way split class sums)
  //   2211840  ticket int [1]
  //   2211872  mf     f32 [8192]
  char* xnbF = ws;
  float* Zr = (float*)(ws + 2097152);
  float* Ur = (float*)(ws + 2129920);
  float* Vr = (float*)(ws + 2162688);
  float* gh16 = (float*)(ws + 2195456);
  int* ticket = (int*)(ws + 2211840);
  float* mf = (float*)(ws + 2211872);

  // gh16 + ticket (16388 B); Zr/Ur/Vr/mf zeroed in k_norm; out stored by
  // k_main's last block.
  hipMemsetAsync(ws + 2195456, 0, 16388, stream);

  k_norm<<<512, 256, 0, stream>>>(data, label, xnbF, gh16, Zr, Ur, Vr, mf);
  k_main<<<512, 512, 0, stream>>>((const short*)xnbF, label, mf, scale, gh16,
                                  Zr, Ur, Vr, ticket, (float*)d_out);
}